// Round 6
// baseline (54011.377 us; speedup 1.0000x reference)
//
#include <hip/hip_runtime.h>
#include <cstdint>
#include <cstddef>

// GRU decoder w/ Bahdanau attention, B=64 L=512 E=128 H=512 ENC=256 V=4 NL=2.
// R6 = R5 + XCD-aware role assignment: block reads HW_REG_XCC_ID, takes a
// per-XCD rank (relaxed agent atomic), and derives (b, j) so that all blocks
// on one XCD share the same weight j-slice (~1.375 MB -> L2-resident; R5
// thrashed L2 with all 4 slices = 5.25 MB > 4 MB and refetched 31 MB/step
// from HBM). Everything else identical to R5.

#define BB   64
#define LL   512
#define EE   128
#define HH   512
#define ED   256
#define VV   4
#define SOS  4

#define NBLK 256
#define NTHR 512

typedef unsigned short ushort8 __attribute__((ext_vector_type(8)));
typedef unsigned int uint;

// ---------------- ws layout (bytes) ----------------
static const size_t OFF_KEYS = 0;          // ushort [64][512][512]  33,554,432
static const size_t OFF_WH   = 33554432;   // ushort [512][512]         524,288
static const size_t OFF_WHH0 = 34078720;   // ushort [1536][512]      1,572,864
static const size_t OFF_WIH1 = 35651584;   // ushort [1536][512]      1,572,864
static const size_t OFF_WHH1 = 37224448;   // ushort [1536][512]      1,572,864
static const size_t OFF_WIHC = 38797312;   // ushort [1536][256]        786,432
static const size_t OFF_GTOK = 39583744;   // float  [6][1536]           36,864
static const size_t OFF_H0   = 39620608;   // float  [64][512]          131,072
static const size_t OFF_H1   = 39751680;   // float  [64][512]          131,072
static const size_t OFF_QQ   = 39882752;   // float  [64][4][512]       524,288
static const size_t OFF_CTXP = 40407040;   // float  [64][4][256]       262,144
static const size_t OFF_SS   = 40669184;   // float  [64][4]              1,024
static const size_t OFF_H0Q  = 40670208;   // float  [64][4][128]       131,072
static const size_t OFF_H1Q  = 40801280;   // float  [64][4][128]       131,072
static const size_t OFF_FLG  = 40932352;   // uint   [256] x 64B lines   16,384
static const size_t OFF_CNT  = 40948736;   // uint   [8] x 64B lines        512
static const size_t OFF_LP   = 40949248;   // float  [512][64][16]    2,097,152
// end ~43 MB

// ---------------- dynamic LDS layout (bytes) ----------------
#define L_KEYS 0          // 131072 swizzled keys quarter [128][512] bf16
#define L_H0F  131072     // 2048  h0 full f32
#define L_H1F  133120     // 2048  h1 full f32
#define L_Q    135168     // 2176  q padded f32 [4][136]
#define L_VV   137344     // 2176  v padded f32
#define L_CTX  139520     // 1024  ctx f32 [256]
#define L_SCB  140544     // 512   scores [128]
#define L_ATB  141056     // 512   exp(scores) [128]
#define L_CT   141568     // 1024  ctmp f32 [256]
#define L_RED  142592     // 64    wave-reduce scratch
#define L_PRED 142656     // 12288 pRed f32 [4][6][128]
#define L_GH0  154944     // 1536  gh0own [3][128]
#define L_GH1  156480     // 1536  gh1own [3][128]
#define L_TOT  158016

// padded q index: quarter p starts at p*136 floats
__device__ __forceinline__ int qidx(int h) { return h + ((h >> 7) << 3); }

// ---------------- helpers ----------------
__device__ __forceinline__ float bfu(unsigned short u) {
  return __uint_as_float(((unsigned)u) << 16);
}
__device__ __forceinline__ float bflo(uint u) { return __uint_as_float(u << 16); }
__device__ __forceinline__ float bfhi(uint u) { return __uint_as_float(u & 0xffff0000u); }
__device__ __forceinline__ unsigned short f2bf(float f) {
  unsigned u = __float_as_uint(f);
  unsigned r = 0x7FFFu + ((u >> 16) & 1u);
  return (unsigned short)((u + r) >> 16);
}
__device__ __forceinline__ float tanh_fast(float x) {
  x = __builtin_amdgcn_fmed3f(x, -10.f, 10.f);
  float t = __builtin_amdgcn_exp2f(x * 2.8853900817779268f);
  return (t - 1.f) * __builtin_amdgcn_rcpf(t + 1.f);
}
__device__ __forceinline__ float sigmoid_fast(float x) {
  x = __builtin_amdgcn_fmed3f(x, -30.f, 30.f);
  float t = __builtin_amdgcn_exp2f(x * -1.4426950408889634f);
  return __builtin_amdgcn_rcpf(1.f + t);
}
__device__ __forceinline__ float exp_fast(float x) {
  return __builtin_amdgcn_exp2f(x * 1.4426950408889634f);
}
__device__ __forceinline__ float gloadf(const float* p) {
  return __hip_atomic_load(p, __ATOMIC_RELAXED, __HIP_MEMORY_SCOPE_AGENT);
}
__device__ __forceinline__ void gstoref(float* p, float v) {
  __hip_atomic_store(p, v, __ATOMIC_RELAXED, __HIP_MEMORY_SCOPE_AGENT);
}
__device__ __forceinline__ uint gloadu(const uint* p) {
  return __hip_atomic_load(p, __ATOMIC_RELAXED, __HIP_MEMORY_SCOPE_AGENT);
}
__device__ __forceinline__ void gstoreu(uint* p, uint v) {
  __hip_atomic_store(p, v, __ATOMIC_RELAXED, __HIP_MEMORY_SCOPE_AGENT);
}

// quad barrier: drain vmem, tid0 publishes flag=gen, spins (relaxed) on the
// 3 siblings' flags.
__device__ __forceinline__ void quad_sync(char* ws, int b, int j, uint gen) {
  asm volatile("s_waitcnt vmcnt(0)" ::: "memory");
  __syncthreads();
  if (threadIdx.x == 0) {
    uint* fl = (uint*)(ws + OFF_FLG);
    gstoreu(fl + (size_t)(b * 4 + j) * 16, gen);
    #pragma unroll
    for (int p = 0; p < 4; ++p) {
      if (p == j) continue;
      while (gloadu(fl + (size_t)(b * 4 + p) * 16) < gen)
        __builtin_amdgcn_s_sleep(4);
    }
  }
  __syncthreads();
}

// ---------------- precompute kernels ----------------

__global__ void k_prep(const float* Wh, const float* Whh0, const float* Wih0,
                       const float* Wih1, const float* Whh1, char* ws) {
  unsigned short* Whbf   = (unsigned short*)(ws + OFF_WH);
  unsigned short* Whh0bf = (unsigned short*)(ws + OFF_WHH0);
  unsigned short* Wih1bf = (unsigned short*)(ws + OFF_WIH1);
  unsigned short* Whh1bf = (unsigned short*)(ws + OFF_WHH1);
  unsigned short* WihCbf = (unsigned short*)(ws + OFF_WIHC);
  const int tot = 262144 + 786432 * 3 + 393216;
  for (int i = blockIdx.x * blockDim.x + threadIdx.x; i < tot; i += gridDim.x * blockDim.x) {
    if (i < 262144) { Whbf[i] = f2bf(Wh[i]); }
    else if (i < 262144 + 786432) { int jj = i - 262144; Whh0bf[jj] = f2bf(Whh0[jj]); }
    else if (i < 262144 + 2 * 786432) { int jj = i - 262144 - 786432; Wih1bf[jj] = f2bf(Wih1[jj]); }
    else if (i < 262144 + 3 * 786432) { int jj = i - 262144 - 2 * 786432; Whh1bf[jj] = f2bf(Whh1[jj]); }
    else {
      int jj = i - 262144 - 3 * 786432;
      int r = jj >> 8, e = jj & 255;
      WihCbf[jj] = f2bf(Wih0[(size_t)r * 384 + 128 + e]);
    }
  }
}

__global__ void k_gitok(const float* emb, const float* Wih0, const float* bih0, char* ws) {
  float* gt = (float*)(ws + OFF_GTOK);
  const int vt = blockIdx.x;
  const int tid = threadIdx.x;
  __shared__ float ev[EE];
  if (tid < EE) ev[tid] = emb[(size_t)vt * EE + tid];
  __syncthreads();
  for (int r = tid; r < 1536; r += 256) {
    float a = bih0[r];
    const float* wr = Wih0 + (size_t)r * 384;
    for (int e = 0; e < EE; ++e) a += wr[e] * ev[e];
    gt[(size_t)vt * 1536 + r] = a;
  }
}

__global__ void k_keys(const float* enc, const float* Ws, char* ws) {
  unsigned short* keys = (unsigned short*)(ws + OFF_KEYS);
  __shared__ float et[32][ED];
  const int tid = threadIdx.x;
  const int row0 = blockIdx.x * 32;
  for (int r = 0; r < 32; ++r) et[r][tid] = enc[(size_t)(row0 + r) * ED + tid];
  __syncthreads();
  for (int hhh = 0; hhh < 2; ++hhh) {
    const int h = hhh * 256 + tid;
    float acc[32];
    #pragma unroll
    for (int ll = 0; ll < 32; ++ll) acc[ll] = 0.f;
    const float4* wrow = (const float4*)(Ws + (size_t)h * ED);
    for (int e4 = 0; e4 < 64; ++e4) {
      float4 w = wrow[e4];
      #pragma unroll
      for (int ll = 0; ll < 32; ++ll) {
        acc[ll] += w.x * et[ll][e4 * 4] + w.y * et[ll][e4 * 4 + 1]
                 + w.z * et[ll][e4 * 4 + 2] + w.w * et[ll][e4 * 4 + 3];
      }
    }
    for (int ll = 0; ll < 32; ++ll)
      keys[(size_t)(row0 + ll) * HH + h] = f2bf(acc[ll]);
  }
}

__global__ void k_init(const float* enc, const float* Winit, const float* binit, char* ws) {
  const int b = blockIdx.x;
  const int tid = threadIdx.x; // 256
  __shared__ float pooled[ED];
  float acc = 0.f;
  for (int l = 0; l < LL; ++l) acc += enc[((size_t)b * LL + l) * ED + tid];
  pooled[tid] = acc * (1.0f / 512.0f);
  __syncthreads();
  float* h0 = (float*)(ws + OFF_H0);
  float* h1 = (float*)(ws + OFF_H1);
  for (int pass = 0; pass < 4; ++pass) {
    const int jj = pass * 256 + tid;
    float a = binit[jj];
    const float* wr = Winit + (size_t)jj * ED;
    for (int e = 0; e < ED; ++e) a += wr[e] * pooled[e];
    const float val = tanh_fast(a);
    const int nl = jj >> 9, h = jj & 511;
    if (nl == 0) h0[(size_t)b * HH + h] = val;
    else h1[(size_t)b * HH + h] = val;
  }
  if (b == 0) {
    uint* fl = (uint*)(ws + OFF_FLG);
    for (int i = tid; i < 4096; i += 256) fl[i] = 0u;
    uint* cnt = (uint*)(ws + OFF_CNT);
    if (tid < 128) cnt[tid] = 0u;
  }
}

// ---------------- main persistent decoder ----------------
__launch_bounds__(NTHR, 1)
__global__ void k_decode(char* ws, const float* enc, const int* targets,
                         const float* vvec, const float* bhh0, const float* bhh1,
                         const float* bih1, const float* Wout) {
  extern __shared__ char smem[];
  const int tid = threadIdx.x;

  // ---- XCD-aware role assignment: j = xcd&3 so each XCD's L2 holds exactly
  // one weight j-slice (~1.375 MB). rank via per-XCD relaxed atomic.
  __shared__ int roleSh[2];
  if (tid == 0) {
    uint xcd;
    asm volatile("s_getreg_b32 %0, hwreg(HW_REG_XCC_ID)" : "=s"(xcd));
    xcd &= 7u;
    uint* cnt = (uint*)(ws + OFF_CNT);
    uint rank = __hip_atomic_fetch_add(cnt + (size_t)xcd * 16, 1u,
                                       __ATOMIC_RELAXED, __HIP_MEMORY_SCOPE_AGENT);
    roleSh[0] = (int)((((xcd >> 2) * 32) + rank) & 63);  // b
    roleSh[1] = (int)(xcd & 3);                          // j
  }
  __syncthreads();
  const int b = roleSh[0], j = roleSh[1];

  const unsigned short* keysg  = (const unsigned short*)(ws + OFF_KEYS);
  const unsigned short* Whbf   = (const unsigned short*)(ws + OFF_WH);
  const unsigned short* Whh0bf = (const unsigned short*)(ws + OFF_WHH0);
  const unsigned short* Wih1bf = (const unsigned short*)(ws + OFF_WIH1);
  const unsigned short* Whh1bf = (const unsigned short*)(ws + OFF_WHH1);
  const unsigned short* WihCbf = (const unsigned short*)(ws + OFF_WIHC);
  const float* gi_tok = (const float*)(ws + OFF_GTOK);

  float* QQgf   = (float*)(ws + OFF_QQ)   + (size_t)b * 2048;  // [4][512]
  float* CTXPgf = (float*)(ws + OFF_CTXP) + (size_t)b * 1024;  // [4][256]
  float* SSg    = (float*)(ws + OFF_SS)   + (size_t)b * 4;     // [4]
  float* H0Qgf  = (float*)(ws + OFF_H0Q)  + (size_t)b * 512;   // [4][128]
  float* H1Qgf  = (float*)(ws + OFF_H1Q)  + (size_t)b * 512;   // [4][128]
  float* lp     = (float*)(ws + OFF_LP);

  float* h0f  = (float*)(smem + L_H0F);
  float* h1f  = (float*)(smem + L_H1F);
  float* qb   = (float*)(smem + L_Q);
  float* vvl  = (float*)(smem + L_VV);
  float* ctx  = (float*)(smem + L_CTX);
  float* scb  = (float*)(smem + L_SCB);
  float* atb  = (float*)(smem + L_ATB);
  float* ctmp = (float*)(smem + L_CT);
  float* wred = (float*)(smem + L_RED);
  float* pRed = (float*)(smem + L_PRED);
  float* gh0own = (float*)(smem + L_GH0);
  float* gh1own = (float*)(smem + L_GH1);

  const int r7 = tid & 127, seg = tid >> 7;

  // ---------- preloads (once) ----------
  // keys quarter -> LDS, swizzled: byte = l*1024 + ((h*2) ^ ((l&7)<<4))
  for (int idx = tid; idx < 8192; idx += NTHR) {
    const int l = idx >> 6, hs = idx & 63;
    ushort8 kv = *(const ushort8*)(keysg + ((size_t)(b * LL + j * 128 + l) * HH + hs * 8));
    *(ushort8*)(smem + L_KEYS + l * 1024 + ((hs * 16) ^ ((l & 7) << 4))) = kv;
  }
  vvl[qidx(tid)] = vvec[tid];
  h0f[tid] = ((const float*)(ws + OFF_H0))[(size_t)b * HH + tid];
  h1f[tid] = ((const float*)(ws + OFF_H1))[(size_t)b * HH + tid];

  // enc quarter slice -> 32 packed regs: thread (e=tid>>1, lh=tid&1), 64 l's
  uint encp[32];
  {
    const int e = tid >> 1, lh = tid & 1;
    const float* ebase = enc + ((size_t)(b * LL + j * 128 + lh * 64)) * ED + e;
    #pragma unroll
    for (int jj = 0; jj < 32; ++jj) {
      float a0 = ebase[(size_t)(2 * jj) * ED];
      float a1 = ebase[(size_t)(2 * jj + 1) * ED];
      encp[jj] = (uint)f2bf(a0) | ((uint)f2bf(a1) << 16);
    }
  }
  // Wh columns for own h1-slice: row tid, cols [j*128, +128) -> 64 uints
  uint whq[64];
  #pragma unroll
  for (int i = 0; i < 64; ++i)
    whq[i] = *(const uint*)(Whbf + (size_t)tid * HH + j * 128 + i * 2);

  __syncthreads();

  // pre-loop: publish q-partials AND initial own h1 slice (phase C of step -1)
  {
    float qr = 0.f;
    #pragma unroll 16
    for (int i = 0; i < 64; ++i)
      qr += bflo(whq[i]) * h1f[j * 128 + 2 * i] + bfhi(whq[i]) * h1f[j * 128 + 2 * i + 1];
    gstoref(QQgf + (size_t)j * 512 + tid, qr);
    if (tid < 128) gstoref(H1Qgf + (size_t)j * 128 + tid, h1f[j * 128 + tid]);
    quad_sync(ws, b, j, 1u);
  }

  for (int t = 0; t < LL; ++t) {
    // ================= PHASE A =================
    {
      // A1: update sibling h1 slices + assemble q from quad partials
      if (tid < 384) {
        const int ps = tid >> 7, i = tid & 127;
        const int p = ps + (ps >= j);
        h1f[p * 128 + i] = gloadf(H1Qgf + (size_t)p * 128 + i);
      }
      {
        float qv = gloadf(QQgf + 0 * 512 + tid) + gloadf(QQgf + 1 * 512 + tid)
                 + gloadf(QQgf + 2 * 512 + tid) + gloadf(QQgf + 3 * 512 + tid);
        qb[qidx(tid)] = qv;
      }
      __syncthreads();

      // A2: gh0/gh1 partials (weights streamed from L2, h from LDS broadcast)
      {
        float acc[6] = {0.f, 0.f, 0.f, 0.f, 0.f, 0.f};
        const int ks = seg * 128;
        #pragma unroll
        for (int g = 0; g < 3; ++g) {
          const ushort8* w0 = (const ushort8*)(Whh0bf + (size_t)(g * 512 + j * 128 + r7) * 512 + ks);
          const ushort8* w1 = (const ushort8*)(Whh1bf + (size_t)(g * 512 + j * 128 + r7) * 512 + ks);
          for (int k8 = 0; k8 < 16; ++k8) {
            ushort8 a8 = w0[k8];
            ushort8 b8 = w1[k8];
            #pragma unroll
            for (int u = 0; u < 8; ++u) {
              const float h0v = h0f[ks + k8 * 8 + u];
              const float h1v = h1f[ks + k8 * 8 + u];
              acc[g]     += bfu(a8[u]) * h0v;
              acc[3 + g] += bfu(b8[u]) * h1v;
            }
          }
        }
        #pragma unroll
        for (int u = 0; u < 6; ++u) pRed[(seg * 6 + u) * 128 + r7] = acc[u];
      }

      // A3: scores for own l-quarter (keys swizzled LDS, q padded LDS)
      {
        const int lloc = tid >> 2, hq = tid & 3;
        const char* kbase = smem + L_KEYS + lloc * 1024;
        const int xo = (lloc & 7) << 4;
        const float* qh = qb + hq * 136;
        const float* vh = vvl + hq * 136;
        float s = 0.f;
        #pragma unroll 4
        for (int i8 = 0; i8 < 16; ++i8) {
          ushort8 kk = *(const ushort8*)(kbase + ((hq * 256 + i8 * 16) ^ xo));
          #pragma unroll
          for (int u = 0; u < 8; ++u)
            s += vh[i8 * 8 + u] * tanh_fast(qh[i8 * 8 + u] + bfu(kk[u]));
        }
        s += __shfl_xor(s, 1);
        s += __shfl_xor(s, 2);
        if (hq == 0) scb[lloc] = s;
      }
      __syncthreads();

      // A4: exp (no max pass: |s| <= sum|v| ~ 20, safe in f32) + local sum
      {
        float e = 0.f;
        if (tid < 128) { e = exp_fast(scb[tid]); atb[tid] = e; }
        float s2 = e;
        #pragma unroll
        for (int off = 32; off >= 1; off >>= 1) s2 += __shfl_xor(s2, off);
        if ((tid & 63) == 0 && tid < 128) wred[tid >> 6] = s2;
      }
      __syncthreads();

      // A5: ctx partial (unnormalized) from enc regs; gh reduce
      {
        const int e = tid >> 1, lh = tid & 1;
        const float* atp = atb + lh * 64;
        float a = 0.f;
        #pragma unroll
        for (int jj = 0; jj < 32; ++jj) {
          uint u = encp[jj];
          a += atp[2 * jj] * bflo(u) + atp[2 * jj + 1] * bfhi(u);
        }
        a += __shfl_xor(a, 1);
        if (lh == 0) ctmp[e] = a;
      }
      if (tid < 384) {
        const int g = tid >> 7, r = tid & 127;
        gh0own[g * 128 + r] = pRed[(0 * 6 + g) * 128 + r] + pRed[(1 * 6 + g) * 128 + r]
                            + pRed[(2 * 6 + g) * 128 + r] + pRed[(3 * 6 + g) * 128 + r]
                            + bhh0[g * 512 + j * 128 + r];
        gh1own[g * 128 + r] = pRed[(0 * 6 + 3 + g) * 128 + r] + pRed[(1 * 6 + 3 + g) * 128 + r]
                            + pRed[(2 * 6 + 3 + g) * 128 + r] + pRed[(3 * 6 + 3 + g) * 128 + r]
                            + bhh1[g * 512 + j * 128 + r];
      }
      __syncthreads();

      // A6: publish ctx partial (f32) + S
      if (tid < 256) gstoref(CTXPgf + (size_t)j * 256 + tid, ctmp[tid]);
      if (tid == 0) gstoref(SSg + j, wred[0] + wred[1]);
    }
    quad_sync(ws, b, j, (uint)(3 * t + 2));

    // ================= PHASE B: ctx merge + gi0 + layer-0 gates ==============
    {
      if (tid < 256) {
        float S4 = gloadf(SSg + 0) + gloadf(SSg + 1) + gloadf(SSg + 2) + gloadf(SSg + 3);
        const float rS = __builtin_amdgcn_rcpf(S4);
        ctx[tid] = (gloadf(CTXPgf + 0 * 256 + tid) + gloadf(CTXPgf + 1 * 256 + tid)
                  + gloadf(CTXPgf + 2 * 256 + tid) + gloadf(CTXPgf + 3 * 256 + tid)) * rS;
      }
      __syncthreads();
      // gi0 partials: rows g*512 + j*128 + r7, K-span [seg*64,+64) of ctx
      {
        float acc[3] = {0.f, 0.f, 0.f};
        const int ks = seg * 64;
        #pragma unroll
        for (int g = 0; g < 3; ++g) {
          const ushort8* w = (const ushort8*)(WihCbf + (size_t)(g * 512 + j * 128 + r7) * 256 + ks);
          for (int k8 = 0; k8 < 8; ++k8) {
            ushort8 a8 = w[k8];
            #pragma unroll
            for (int u = 0; u < 8; ++u)
              acc[g] += bfu(a8[u]) * ctx[ks + k8 * 8 + u];
          }
        }
        #pragma unroll
        for (int g = 0; g < 3; ++g) pRed[(seg * 6 + g) * 128 + r7] = acc[g];
      }
      __syncthreads();
      if (tid < 128) {
        const int r = tid;
        const int tok = (t == 0) ? SOS : targets[(size_t)b * LL + t - 1];
        const float* gt = gi_tok + (size_t)tok * 1536 + j * 128 + r;
        float gi[3];
        #pragma unroll
        for (int g = 0; g < 3; ++g)
          gi[g] = pRed[(0 * 6 + g) * 128 + r] + pRed[(1 * 6 + g) * 128 + r]
                + pRed[(2 * 6 + g) * 128 + r] + pRed[(3 * 6 + g) * 128 + r]
                + gt[g * 512];
        const float rg = sigmoid_fast(gi[0] + gh0own[0 * 128 + r]);
        const float zg = sigmoid_fast(gi[1] + gh0own[1 * 128 + r]);
        const float ng = tanh_fast(gi[2] + rg * gh0own[2 * 128 + r]);
        h0f[j * 128 + r] = (1.f - zg) * ng + zg * h0f[j * 128 + r];
      }
      __syncthreads();
      if (tid < 128) gstoref(H0Qgf + (size_t)j * 128 + tid, h0f[j * 128 + tid]);
    }
    quad_sync(ws, b, j, (uint)(3 * t + 3));

    // update sibling h0 slices
    if (tid < 384) {
      const int ps = tid >> 7, i = tid & 127;
      const int p = ps + (ps >= j);
      h0f[p * 128 + i] = gloadf(H0Qgf + (size_t)p * 128 + i);
    }
    __syncthreads();

    // ================= PHASE C: gi1 + layer-1 gates + qpart + logits =========
    {
      // gi1 partials: rows g*512 + j*128 + r7, K-span [seg*128,+128) of h0f
      {
        float acc[3] = {0.f, 0.f, 0.f};
        const int ks = seg * 128;
        #pragma unroll
        for (int g = 0; g < 3; ++g) {
          const ushort8* w = (const ushort8*)(Wih1bf + (size_t)(g * 512 + j * 128 + r7) * 512 + ks);
          for (int k8 = 0; k8 < 16; ++k8) {
            ushort8 a8 = w[k8];
            #pragma unroll
            for (int u = 0; u < 8; ++u)
              acc[g] += bfu(a8[u]) * h0f[ks + k8 * 8 + u];
          }
        }
        #pragma unroll
        for (int g = 0; g < 3; ++g) pRed[(seg * 6 + g) * 128 + r7] = acc[g];
      }
      __syncthreads();
      if (tid < 128) {
        const int r = tid;
        float gi[3];
        #pragma unroll
        for (int g = 0; g < 3; ++g)
          gi[g] = pRed[(0 * 6 + g) * 128 + r] + pRed[(1 * 6 + g) * 128 + r]
                + pRed[(2 * 6 + g) * 128 + r] + pRed[(3 * 6 + g) * 128 + r]
                + bih1[g * 512 + j * 128 + r];
        const float rg = sigmoid_fast(gi[0] + gh1own[0 * 128 + r]);
        const float zg = sigmoid_fast(gi[1] + gh1own[1 * 128 + r]);
        const float ng = tanh_fast(gi[2] + rg * gh1own[2 * 128 + r]);
        h1f[j * 128 + r] = (1.f - zg) * ng + zg * h1f[j * 128 + r];
      }
      __syncthreads();
      // qpart (Wh columns in regs . new own h1 slice) — published straight
      {
        float qr = 0.f;
        #pragma unroll 16
        for (int i = 0; i < 64; ++i)
          qr += bflo(whq[i]) * h1f[j * 128 + 2 * i] + bfhi(whq[i]) * h1f[j * 128 + 2 * i + 1];
        gstoref(QQgf + (size_t)j * 512 + tid, qr);
      }
      if (tid < 128) gstoref(H1Qgf + (size_t)j * 128 + tid, h1f[j * 128 + tid]);
      // logit partials: threads 128..255 -> (v = g>>5, lanes g&31 over 4 elems)
      if (tid >= 128 && tid < 256) {
        const int g = tid - 128;
        const int v = g >> 5, i = g & 31;
        float a = 0.f;
        #pragma unroll
        for (int k = 0; k < 4; ++k)
          a += Wout[(size_t)v * HH + j * 128 + i * 4 + k] * h1f[j * 128 + i * 4 + k];
        a += __shfl_xor(a, 16); a += __shfl_xor(a, 8);
        a += __shfl_xor(a, 4);  a += __shfl_xor(a, 2); a += __shfl_xor(a, 1);
        if (i == 0) lp[((size_t)t * BB + b) * 16 + j * 4 + v] = a;
      }
    }
    quad_sync(ws, b, j, (uint)(3 * t + 4));
  }
}

// sum logit partials -> out
__global__ void k_lsum(const char* ws, const float* bout, float* out) {
  const float* lp = (const float*)(ws + OFF_LP);
  const int i = blockIdx.x * 256 + threadIdx.x;
  if (i >= BB * LL * VV) return;
  const int v = i & 3, t = (i >> 2) & 511, b = i >> 11;
  float a = bout[v];
  #pragma unroll
  for (int jj = 0; jj < 4; ++jj)
    a += lp[((size_t)t * BB + b) * 16 + jj * 4 + v];
  out[i] = a;
}

// ---------------- launch ----------------
extern "C" void kernel_launch(void* const* d_in, const int* in_sizes, int n_in,
                              void* d_out, int out_size, void* d_ws, size_t ws_size,
                              hipStream_t stream) {
  char* ws = (char*)d_ws;
  const float* enc     = (const float*)d_in[0];
  const int*   targets = (const int*)d_in[1];
  const float* emb   = (const float*)d_in[4];
  const float* Wh    = (const float*)d_in[5];
  const float* Ws    = (const float*)d_in[6];
  const float* vvec  = (const float*)d_in[7];
  const float* Wih0  = (const float*)d_in[8];
  const float* Whh0  = (const float*)d_in[9];
  const float* bih0  = (const float*)d_in[10];
  const float* bhh0  = (const float*)d_in[11];
  const float* Wih1  = (const float*)d_in[12];
  const float* Whh1  = (const float*)d_in[13];
  const float* bih1  = (const float*)d_in[14];
  const float* bhh1  = (const float*)d_in[15];
  const float* Wout  = (const float*)d_in[16];
  const float* bout  = (const float*)d_in[17];
  const float* Winit = (const float*)d_in[18];
  const float* binit = (const float*)d_in[19];

  k_prep <<<1024, 256, 0, stream>>>(Wh, Whh0, Wih0, Wih1, Whh1, ws);
  k_gitok<<<6,    256, 0, stream>>>(emb, Wih0, bih0, ws);
  k_keys <<<1024, 256, 0, stream>>>(enc, Ws, ws);
  k_init <<<64,   256, 0, stream>>>(enc, Winit, binit, ws);

  (void)hipFuncSetAttribute((const void*)k_decode,
                            hipFuncAttributeMaxDynamicSharedMemorySize, L_TOT);

  {
    void* kws = (void*)ws;
    void* ken = (void*)enc;
    void* ktg = (void*)targets;
    void* kvv = (void*)vvec;
    void* kb0 = (void*)bhh0;
    void* kb1 = (void*)bhh1;
    void* kbi = (void*)bih1;
    void* kwo = (void*)Wout;
    void* args[] = { &kws, &ken, &ktg, &kvv, &kb0, &kb1, &kbi, &kwo };
    hipError_t ce = hipLaunchCooperativeKernel((const void*)k_decode, dim3(NBLK), dim3(NTHR),
                                               args, L_TOT, stream);
    if (ce != hipSuccess) {
      // 256 blocks x (512 thr, 158KB LDS) = 1 block/CU on 256 CUs: co-resident
      k_decode<<<dim3(NBLK), dim3(NTHR), L_TOT, stream>>>(ws, enc, targets, vvec,
                                                          bhh0, bhh1, bih1, Wout);
    }
  }

  k_lsum<<<512, 256, 0, stream>>>(ws, bout, (float*)d_out);
}

// Round 7
// 49895.810 us; speedup vs baseline: 1.0825x; 1.0825x over previous
//
#include <hip/hip_runtime.h>
#include <cstdint>
#include <cstddef>

// GRU decoder w/ Bahdanau attention, B=64 L=512 E=128 H=512 ENC=256 V=4 NL=2.
// R7: OCTET decomposition. 512 blocks x 256 threads, 2 blocks/CU co-resident
// (latency overlap). Block (b, j=XCC_ID) owns keys l-eighth (64KB LDS) and
// h-slice [j*64,+64) of both GRU layers; per-XCD weight slice ~690KB is
// L2-resident. 3 octet flag-barriers/step with 8 PARALLEL pollers.
// Recurrent state f32; exchanges bf16-packed (q, h) / f32 (ctx).

#define BB   64
#define LL   512
#define EE   128
#define HH   512
#define ED   256
#define VV   4
#define SOS  4

#define NBLK 512
#define NTHR 256

typedef unsigned short ushort8 __attribute__((ext_vector_type(8)));
typedef unsigned int uint;

// ---------------- ws layout (bytes) ----------------
static const size_t OFF_KEYS = 0;          // ushort [64][512][512]  33,554,432
static const size_t OFF_WH   = 33554432;   // ushort [512][512]         524,288
static const size_t OFF_WHH0 = 34078720;   // ushort [1536][512]      1,572,864
static const size_t OFF_WIH1 = 35651584;   // ushort [1536][512]      1,572,864
static const size_t OFF_WHH1 = 37224448;   // ushort [1536][512]      1,572,864
static const size_t OFF_WIHC = 38797312;   // ushort [1536][256]        786,432
static const size_t OFF_GTOK = 39583744;   // float  [6][1536]           36,864
static const size_t OFF_H0   = 39620608;   // float  [64][512]          131,072
static const size_t OFF_H1   = 39751680;   // float  [64][512]          131,072
static const size_t OFF_QQ   = 39882752;   // uint   [64][8][256]       524,288
static const size_t OFF_CTXP = 40407040;   // float  [64][8][256]       524,288
static const size_t OFF_SS   = 40931328;   // float  [64][8]              2,048
static const size_t OFF_H0Q  = 40933376;   // uint   [64][8][32]         65,536
static const size_t OFF_H1Q  = 40998912;   // uint   [64][8][32]         65,536
static const size_t OFF_FLG  = 41064448;   // 64*8 x 64B                 32,768
static const size_t OFF_CNT  = 41097216;   // 8 x 64B                       512
static const size_t OFF_LP   = 41097728;   // f32 [512][64][8][4]     4,194,304
// end ~45.3 MB

// ---------------- dynamic LDS layout (bytes) ----------------
#define L_KEYS 0          // 65536 swizzled keys eighth [64][512] bf16
#define L_H0F  65536      // 1024  h0 full bf16-packed uint[256]
#define L_H1F  66560      // 1024  h1 full bf16-packed uint[256]
#define L_QB   67584      // 2112  q f32 padded [4][132]
#define L_VV   69696      // 2112  v f32 padded [4][132]
#define L_CTX  71808      // 1024  ctx f32 [256]
#define L_SCB  72832      // 256   scores [64]
#define L_ATB  73088      // 256   exp(scores) [64]
#define L_RED  73344      // 64    reduce scratch
#define L_PRED 73408      // 3072  pRed f32 [4][3][64]
#define L_GH0  76480      // 768   gh0own [3][64]
#define L_GH1  77248      // 768   gh1own [3][64]
#define L_H0O  78016      // 256   h0own f32 [64]
#define L_H1O  78272      // 256   h1own f32 [64]
#define L_TOT  78528      // x2 blocks/CU = 157,056 <= 160K

// ---------------- helpers ----------------
__device__ __forceinline__ float bfu(unsigned short u) {
  return __uint_as_float(((unsigned)u) << 16);
}
__device__ __forceinline__ float bflo(uint u) { return __uint_as_float(u << 16); }
__device__ __forceinline__ float bfhi(uint u) { return __uint_as_float(u & 0xffff0000u); }
__device__ __forceinline__ unsigned short f2bf(float f) {
  unsigned u = __float_as_uint(f);
  unsigned r = 0x7FFFu + ((u >> 16) & 1u);
  return (unsigned short)((u + r) >> 16);
}
__device__ __forceinline__ uint packbf(float a, float b) {
  return (uint)f2bf(a) | ((uint)f2bf(b) << 16);
}
__device__ __forceinline__ float tanh_fast(float x) {
  x = __builtin_amdgcn_fmed3f(x, -10.f, 10.f);
  float t = __builtin_amdgcn_exp2f(x * 2.8853900817779268f);
  return (t - 1.f) * __builtin_amdgcn_rcpf(t + 1.f);
}
__device__ __forceinline__ float sigmoid_fast(float x) {
  x = __builtin_amdgcn_fmed3f(x, -30.f, 30.f);
  float t = __builtin_amdgcn_exp2f(x * -1.4426950408889634f);
  return __builtin_amdgcn_rcpf(1.f + t);
}
__device__ __forceinline__ float exp_fast(float x) {
  return __builtin_amdgcn_exp2f(x * 1.4426950408889634f);
}
__device__ __forceinline__ float gloadf(const float* p) {
  return __hip_atomic_load(p, __ATOMIC_RELAXED, __HIP_MEMORY_SCOPE_AGENT);
}
__device__ __forceinline__ void gstoref(float* p, float v) {
  __hip_atomic_store(p, v, __ATOMIC_RELAXED, __HIP_MEMORY_SCOPE_AGENT);
}
__device__ __forceinline__ uint gloadu(const uint* p) {
  return __hip_atomic_load(p, __ATOMIC_RELAXED, __HIP_MEMORY_SCOPE_AGENT);
}
__device__ __forceinline__ void gstoreu(uint* p, uint v) {
  __hip_atomic_store(p, v, __ATOMIC_RELAXED, __HIP_MEMORY_SCOPE_AGENT);
}

// octet barrier: drain vmem; tid0 publishes flag=gen; threads 0..7 poll the
// 8 member flags IN PARALLEL (wait = max member skew, not sum).
__device__ __forceinline__ void octet_sync(char* ws, int b, int j, uint gen) {
  asm volatile("s_waitcnt vmcnt(0)" ::: "memory");
  __syncthreads();
  const int tid = threadIdx.x;
  uint* fl = (uint*)(ws + OFF_FLG);
  if (tid == 0)
    gstoreu(fl + (size_t)(b * 8 + j) * 16, gen);
  if (tid < 8 && tid != j) {
    while (gloadu(fl + (size_t)(b * 8 + tid) * 16) < gen)
      __builtin_amdgcn_s_sleep(4);
  }
  __syncthreads();
}

// ---------------- precompute kernels ----------------

__global__ void k_prep(const float* Wh, const float* Whh0, const float* Wih0,
                       const float* Wih1, const float* Whh1, char* ws) {
  unsigned short* Whbf   = (unsigned short*)(ws + OFF_WH);
  unsigned short* Whh0bf = (unsigned short*)(ws + OFF_WHH0);
  unsigned short* Wih1bf = (unsigned short*)(ws + OFF_WIH1);
  unsigned short* Whh1bf = (unsigned short*)(ws + OFF_WHH1);
  unsigned short* WihCbf = (unsigned short*)(ws + OFF_WIHC);
  const int tot = 262144 + 786432 * 3 + 393216;
  for (int i = blockIdx.x * blockDim.x + threadIdx.x; i < tot; i += gridDim.x * blockDim.x) {
    if (i < 262144) { Whbf[i] = f2bf(Wh[i]); }
    else if (i < 262144 + 786432) { int jj = i - 262144; Whh0bf[jj] = f2bf(Whh0[jj]); }
    else if (i < 262144 + 2 * 786432) { int jj = i - 262144 - 786432; Wih1bf[jj] = f2bf(Wih1[jj]); }
    else if (i < 262144 + 3 * 786432) { int jj = i - 262144 - 2 * 786432; Whh1bf[jj] = f2bf(Whh1[jj]); }
    else {
      int jj = i - 262144 - 3 * 786432;
      int r = jj >> 8, e = jj & 255;
      WihCbf[jj] = f2bf(Wih0[(size_t)r * 384 + 128 + e]);
    }
  }
}

__global__ void k_gitok(const float* emb, const float* Wih0, const float* bih0, char* ws) {
  float* gt = (float*)(ws + OFF_GTOK);
  const int vt = blockIdx.x;
  const int tid = threadIdx.x;
  __shared__ float ev[EE];
  if (tid < EE) ev[tid] = emb[(size_t)vt * EE + tid];
  __syncthreads();
  for (int r = tid; r < 1536; r += 256) {
    float a = bih0[r];
    const float* wr = Wih0 + (size_t)r * 384;
    for (int e = 0; e < EE; ++e) a += wr[e] * ev[e];
    gt[(size_t)vt * 1536 + r] = a;
  }
}

__global__ void k_keys(const float* enc, const float* Ws, char* ws) {
  unsigned short* keys = (unsigned short*)(ws + OFF_KEYS);
  __shared__ float et[32][ED];
  const int tid = threadIdx.x;
  const int row0 = blockIdx.x * 32;
  for (int r = 0; r < 32; ++r) et[r][tid] = enc[(size_t)(row0 + r) * ED + tid];
  __syncthreads();
  for (int hhh = 0; hhh < 2; ++hhh) {
    const int h = hhh * 256 + tid;
    float acc[32];
    #pragma unroll
    for (int ll = 0; ll < 32; ++ll) acc[ll] = 0.f;
    const float4* wrow = (const float4*)(Ws + (size_t)h * ED);
    for (int e4 = 0; e4 < 64; ++e4) {
      float4 w = wrow[e4];
      #pragma unroll
      for (int ll = 0; ll < 32; ++ll) {
        acc[ll] += w.x * et[ll][e4 * 4] + w.y * et[ll][e4 * 4 + 1]
                 + w.z * et[ll][e4 * 4 + 2] + w.w * et[ll][e4 * 4 + 3];
      }
    }
    for (int ll = 0; ll < 32; ++ll)
      keys[(size_t)(row0 + ll) * HH + h] = f2bf(acc[ll]);
  }
}

__global__ void k_init(const float* enc, const float* Winit, const float* binit, char* ws) {
  const int b = blockIdx.x;
  const int tid = threadIdx.x; // 256
  __shared__ float pooled[ED];
  float acc = 0.f;
  for (int l = 0; l < LL; ++l) acc += enc[((size_t)b * LL + l) * ED + tid];
  pooled[tid] = acc * (1.0f / 512.0f);
  __syncthreads();
  float* h0 = (float*)(ws + OFF_H0);
  float* h1 = (float*)(ws + OFF_H1);
  for (int pass = 0; pass < 4; ++pass) {
    const int jj = pass * 256 + tid;
    float a = binit[jj];
    const float* wr = Winit + (size_t)jj * ED;
    for (int e = 0; e < ED; ++e) a += wr[e] * pooled[e];
    const float val = tanh_fast(a);
    const int nl = jj >> 9, h = jj & 511;
    if (nl == 0) h0[(size_t)b * HH + h] = val;
    else h1[(size_t)b * HH + h] = val;
  }
  if (b == 0) {
    uint* fl = (uint*)(ws + OFF_FLG);
    for (int i = tid; i < 8192; i += 256) fl[i] = 0u;
    uint* cnt = (uint*)(ws + OFF_CNT);
    if (tid < 128) cnt[tid] = 0u;
  }
}

// ---------------- main persistent decoder ----------------
__launch_bounds__(NTHR, 2)
__global__ void k_decode(char* ws, const float* enc, const int* targets,
                         const float* vvec, const float* bhh0, const float* bhh1,
                         const float* bih1, const float* Wout) {
  extern __shared__ char smem[];
  const int tid = threadIdx.x;

  // XCD-aware roles: j = XCC_ID (weight slice pinned to XCD L2), b = rank.
  __shared__ int roleSh[2];
  if (tid == 0) {
    uint xcd;
    asm volatile("s_getreg_b32 %0, hwreg(HW_REG_XCC_ID)" : "=s"(xcd));
    xcd &= 7u;
    uint* cnt = (uint*)(ws + OFF_CNT);
    uint rank = __hip_atomic_fetch_add(cnt + (size_t)xcd * 16, 1u,
                                       __ATOMIC_RELAXED, __HIP_MEMORY_SCOPE_AGENT);
    roleSh[0] = (int)(rank & 63);
    roleSh[1] = (int)xcd;
  }
  __syncthreads();
  const int b = roleSh[0], j = roleSh[1];

  const unsigned short* keysg  = (const unsigned short*)(ws + OFF_KEYS);
  const unsigned short* Whbf   = (const unsigned short*)(ws + OFF_WH);
  const unsigned short* Whh0bf = (const unsigned short*)(ws + OFF_WHH0);
  const unsigned short* Wih1bf = (const unsigned short*)(ws + OFF_WIH1);
  const unsigned short* Whh1bf = (const unsigned short*)(ws + OFF_WHH1);
  const unsigned short* WihCbf = (const unsigned short*)(ws + OFF_WIHC);
  const float* gi_tok = (const float*)(ws + OFF_GTOK);

  uint*  QQg   = (uint*)(ws + OFF_QQ)   + (size_t)b * 2048;  // [8][256]
  float* CTXPg = (float*)(ws + OFF_CTXP) + (size_t)b * 2048; // [8][256]
  float* SSg   = (float*)(ws + OFF_SS)  + (size_t)b * 8;     // [8]
  uint*  H0Qg  = (uint*)(ws + OFF_H0Q)  + (size_t)b * 256;   // [8][32]
  uint*  H1Qg  = (uint*)(ws + OFF_H1Q)  + (size_t)b * 256;   // [8][32]
  float* lp    = (float*)(ws + OFF_LP);

  uint*  h0u   = (uint*)(smem + L_H0F);
  uint*  h1u   = (uint*)(smem + L_H1F);
  float* qbf   = (float*)(smem + L_QB);
  float* vvf   = (float*)(smem + L_VV);
  float* ctx   = (float*)(smem + L_CTX);
  float* scb   = (float*)(smem + L_SCB);
  float* atb   = (float*)(smem + L_ATB);
  float* wred  = (float*)(smem + L_RED);
  float* pRed  = (float*)(smem + L_PRED);
  float* gh0own = (float*)(smem + L_GH0);
  float* gh1own = (float*)(smem + L_GH1);
  float* h0own = (float*)(smem + L_H0O);
  float* h1own = (float*)(smem + L_H1O);

  // ---------- preloads (once) ----------
  // keys eighth -> LDS swizzled: byte = l*1024 + ((h*2) ^ ((l&7)<<4))
  for (int c = tid; c < 4096; c += NTHR) {
    const int l = c >> 6, hs = c & 63;
    ushort8 kv = *(const ushort8*)(keysg + ((size_t)(b * LL + j * 64 + l) * HH + hs * 8));
    *(ushort8*)(smem + L_KEYS + l * 1024 + ((hs * 16) ^ ((l & 7) << 4))) = kv;
  }
  for (int h = tid; h < 512; h += NTHR)
    vvf[(h >> 7) * 132 + (h & 127)] = vvec[h];
  {
    const float* H0g = (const float*)(ws + OFF_H0) + (size_t)b * HH;
    const float* H1g = (const float*)(ws + OFF_H1) + (size_t)b * HH;
    h0u[tid] = packbf(H0g[2 * tid], H0g[2 * tid + 1]);
    h1u[tid] = packbf(H1g[2 * tid], H1g[2 * tid + 1]);
    if (tid < 64) {
      h0own[tid] = H0g[j * 64 + tid];
      h1own[tid] = H1g[j * 64 + tid];
    }
  }
  // enc slice -> regs: thread e=tid holds 64 l (packed pairs)
  uint encp[32];
  {
    const float* ebase = enc + ((size_t)(b * LL + j * 64)) * ED + tid;
    #pragma unroll
    for (int k = 0; k < 32; ++k)
      encp[k] = packbf(ebase[(size_t)(2 * k) * ED], ebase[(size_t)(2 * k + 1) * ED]);
  }
  // Wh rows 2t,2t+1, cols [j*64,+64) -> 64 uints
  uint whq[64];
  #pragma unroll
  for (int i = 0; i < 32; ++i) {
    whq[i]      = *(const uint*)(Whbf + (size_t)(2 * tid) * HH + j * 64 + 2 * i);
    whq[32 + i] = *(const uint*)(Whbf + (size_t)(2 * tid + 1) * HH + j * 64 + 2 * i);
  }
  __syncthreads();

  // pre-loop: publish q-parts + own h1 slice (phase C of step -1)
  {
    float q0 = 0.f, q1 = 0.f;
    #pragma unroll
    for (int i = 0; i < 32; ++i) {
      const float hl = h1own[2 * i], hh = h1own[2 * i + 1];
      q0 += bflo(whq[i]) * hl + bfhi(whq[i]) * hh;
      q1 += bflo(whq[32 + i]) * hl + bfhi(whq[32 + i]) * hh;
    }
    gstoreu(QQg + (size_t)j * 256 + tid, packbf(q0, q1));
    if (tid < 32) gstoreu(H1Qg + (size_t)j * 32 + tid,
                          packbf(h1own[2 * tid], h1own[2 * tid + 1]));
  }
  octet_sync(ws, b, j, 1u);

  for (int t = 0; t < LL; ++t) {
    // ====== A1: q assembly + sibling h1 update ======
    {
      float qlo = 0.f, qhi = 0.f;
      #pragma unroll
      for (int p = 0; p < 8; ++p) {
        uint u = gloadu(QQg + (size_t)p * 256 + tid);
        qlo += bflo(u); qhi += bfhi(u);
      }
      const int hq = tid >> 6, i2 = (tid & 63) * 2;
      qbf[hq * 132 + i2] = qlo;
      qbf[hq * 132 + i2 + 1] = qhi;
      if (tid < 224) {
        const int ps = tid >> 5, i = tid & 31;
        const int p = ps + (ps >= j);
        h1u[p * 32 + i] = gloadu(H1Qg + (size_t)p * 32 + i);
      }
    }
    __syncthreads();

    // ====== A2: gh0/gh1 K-half partials (k8-outer, h read once) ======
    {
      const int mat = tid >> 7, seg = (tid >> 6) & 1, r = tid & 63;
      const unsigned short* W = mat ? Whh1bf : Whh0bf;
      const uint* hsrc = (mat ? h1u : h0u) + seg * 128;
      const ushort8* w0 = (const ushort8*)(W + (size_t)(0 * 512 + j * 64 + r) * 512 + seg * 256);
      const ushort8* w1 = (const ushort8*)(W + (size_t)(1 * 512 + j * 64 + r) * 512 + seg * 256);
      const ushort8* w2 = (const ushort8*)(W + (size_t)(2 * 512 + j * 64 + r) * 512 + seg * 256);
      float a0 = 0.f, a1 = 0.f, a2 = 0.f;
      for (int k8 = 0; k8 < 32; ++k8) {
        const uint4 hu = *(const uint4*)(hsrc + k8 * 4);
        const ushort8 u0 = w0[k8], u1 = w1[k8], u2 = w2[k8];
        float hv[8];
        hv[0] = bflo(hu.x); hv[1] = bfhi(hu.x); hv[2] = bflo(hu.y); hv[3] = bfhi(hu.y);
        hv[4] = bflo(hu.z); hv[5] = bfhi(hu.z); hv[6] = bflo(hu.w); hv[7] = bfhi(hu.w);
        #pragma unroll
        for (int u = 0; u < 8; ++u) {
          a0 += bfu(u0[u]) * hv[u];
          a1 += bfu(u1[u]) * hv[u];
          a2 += bfu(u2[u]) * hv[u];
        }
      }
      pRed[((mat * 2 + seg) * 3 + 0) * 64 + r] = a0;
      pRed[((mat * 2 + seg) * 3 + 1) * 64 + r] = a1;
      pRed[((mat * 2 + seg) * 3 + 2) * 64 + r] = a2;
    }

    // ====== A3: scores for own l-eighth ======
    {
      const int lloc = tid >> 2, hq = tid & 3;
      const char* kbase = smem + L_KEYS + lloc * 1024;
      const int xo = (lloc & 7) << 4;
      const float* qh = qbf + hq * 132;
      const float* vh = vvf + hq * 132;
      float s = 0.f;
      for (int i8 = 0; i8 < 16; ++i8) {
        ushort8 kk = *(const ushort8*)(kbase + ((hq * 256 + i8 * 16) ^ xo));
        const float* q8 = qh + i8 * 8;
        const float* v8 = vh + i8 * 8;
        #pragma unroll
        for (int u = 0; u < 8; ++u)
          s += v8[u] * tanh_fast(q8[u] + bfu(kk[u]));
      }
      s += __shfl_xor(s, 1);
      s += __shfl_xor(s, 2);
      if (hq == 0) scb[lloc] = s;
    }
    __syncthreads();

    // ====== A4: exp (no max pass; |s| <~ 20) + sum -> SS ======
    if (tid < 64) {
      float e = exp_fast(scb[tid]);
      atb[tid] = e;
      float s2 = e;
      #pragma unroll
      for (int off = 32; off >= 1; off >>= 1) s2 += __shfl_xor(s2, off);
      if (tid == 0) gstoref(SSg + j, s2);
    }
    __syncthreads();

    // ====== A5: ctx partial (publish) + gh reduce ======
    {
      float a = 0.f;
      #pragma unroll
      for (int k = 0; k < 32; ++k) {
        uint u = encp[k];
        a += atb[2 * k] * bflo(u) + atb[2 * k + 1] * bfhi(u);
      }
      gstoref(CTXPg + (size_t)j * 256 + tid, a);
    }
    for (int o = tid; o < 384; o += NTHR) {
      const int m = (o >= 192) ? 1 : 0, oo = o - m * 192, g = oo >> 6, r = oo & 63;
      const float v = pRed[((m * 2 + 0) * 3 + g) * 64 + r]
                    + pRed[((m * 2 + 1) * 3 + g) * 64 + r]
                    + (m ? bhh1 : bhh0)[g * 512 + j * 64 + r];
      (m ? gh1own : gh0own)[g * 64 + r] = v;
    }
    octet_sync(ws, b, j, (uint)(3 * t + 2));

    // ====== B: ctx merge + gi0 + layer-0 gates ======
    {
      float cp0 = gloadf(CTXPg + 0 * 256 + tid), cp1 = gloadf(CTXPg + 1 * 256 + tid);
      float cp2 = gloadf(CTXPg + 2 * 256 + tid), cp3 = gloadf(CTXPg + 3 * 256 + tid);
      float cp4 = gloadf(CTXPg + 4 * 256 + tid), cp5 = gloadf(CTXPg + 5 * 256 + tid);
      float cp6 = gloadf(CTXPg + 6 * 256 + tid), cp7 = gloadf(CTXPg + 7 * 256 + tid);
      if (tid < 8) wred[tid] = gloadf(SSg + tid);
      __syncthreads();
      const float S8 = ((wred[0] + wred[1]) + (wred[2] + wred[3]))
                     + ((wred[4] + wred[5]) + (wred[6] + wred[7]));
      const float rS = __builtin_amdgcn_rcpf(S8);
      ctx[tid] = (((cp0 + cp1) + (cp2 + cp3)) + ((cp4 + cp5) + (cp6 + cp7))) * rS;
    }
    __syncthreads();
    {
      const int r = tid & 63, q4 = tid >> 6;
      const ushort8* w0 = (const ushort8*)(WihCbf + (size_t)(0 * 512 + j * 64 + r) * 256 + q4 * 64);
      const ushort8* w1 = (const ushort8*)(WihCbf + (size_t)(1 * 512 + j * 64 + r) * 256 + q4 * 64);
      const ushort8* w2 = (const ushort8*)(WihCbf + (size_t)(2 * 512 + j * 64 + r) * 256 + q4 * 64);
      const float* cx = ctx + q4 * 64;
      float a0 = 0.f, a1 = 0.f, a2 = 0.f;
      for (int k8 = 0; k8 < 8; ++k8) {
        const ushort8 u0 = w0[k8], u1 = w1[k8], u2 = w2[k8];
        #pragma unroll
        for (int u = 0; u < 8; ++u) {
          const float c = cx[k8 * 8 + u];
          a0 += bfu(u0[u]) * c; a1 += bfu(u1[u]) * c; a2 += bfu(u2[u]) * c;
        }
      }
      pRed[(q4 * 3 + 0) * 64 + r] = a0;
      pRed[(q4 * 3 + 1) * 64 + r] = a1;
      pRed[(q4 * 3 + 2) * 64 + r] = a2;
    }
    __syncthreads();
    if (tid < 64) {
      const int r = tid;
      const int tok = (t == 0) ? SOS : targets[(size_t)b * LL + t - 1];
      const float* gt = gi_tok + (size_t)tok * 1536 + j * 64 + r;
      const float g0 = pRed[(0 * 3 + 0) * 64 + r] + pRed[(1 * 3 + 0) * 64 + r]
                     + pRed[(2 * 3 + 0) * 64 + r] + pRed[(3 * 3 + 0) * 64 + r] + gt[0];
      const float g1 = pRed[(0 * 3 + 1) * 64 + r] + pRed[(1 * 3 + 1) * 64 + r]
                     + pRed[(2 * 3 + 1) * 64 + r] + pRed[(3 * 3 + 1) * 64 + r] + gt[512];
      const float g2 = pRed[(0 * 3 + 2) * 64 + r] + pRed[(1 * 3 + 2) * 64 + r]
                     + pRed[(2 * 3 + 2) * 64 + r] + pRed[(3 * 3 + 2) * 64 + r] + gt[1024];
      const float rg = sigmoid_fast(g0 + gh0own[r]);
      const float zg = sigmoid_fast(g1 + gh0own[64 + r]);
      const float ng = tanh_fast(g2 + rg * gh0own[128 + r]);
      h0own[r] = (1.f - zg) * ng + zg * h0own[r];
    }
    __syncthreads();
    if (tid < 32) {
      const uint pk = packbf(h0own[2 * tid], h0own[2 * tid + 1]);
      h0u[j * 32 + tid] = pk;
      gstoreu(H0Qg + (size_t)j * 32 + tid, pk);
    }
    octet_sync(ws, b, j, (uint)(3 * t + 3));

    // ====== C: sibling h0 + gi1 + layer-1 gates + qpart + logits ======
    if (tid < 224) {
      const int ps = tid >> 5, i = tid & 31;
      const int p = ps + (ps >= j);
      h0u[p * 32 + i] = gloadu(H0Qg + (size_t)p * 32 + i);
    }
    __syncthreads();
    {
      const int r = tid & 63, s4 = tid >> 6;
      const ushort8* w0 = (const ushort8*)(Wih1bf + (size_t)(0 * 512 + j * 64 + r) * 512 + s4 * 128);
      const ushort8* w1 = (const ushort8*)(Wih1bf + (size_t)(1 * 512 + j * 64 + r) * 512 + s4 * 128);
      const ushort8* w2 = (const ushort8*)(Wih1bf + (size_t)(2 * 512 + j * 64 + r) * 512 + s4 * 128);
      const uint* hsrc = h0u + s4 * 64;
      float a0 = 0.f, a1 = 0.f, a2 = 0.f;
      for (int k8 = 0; k8 < 16; ++k8) {
        const uint4 hu = *(const uint4*)(hsrc + k8 * 4);
        const ushort8 u0 = w0[k8], u1 = w1[k8], u2 = w2[k8];
        float hv[8];
        hv[0] = bflo(hu.x); hv[1] = bfhi(hu.x); hv[2] = bflo(hu.y); hv[3] = bfhi(hu.y);
        hv[4] = bflo(hu.z); hv[5] = bfhi(hu.z); hv[6] = bflo(hu.w); hv[7] = bfhi(hu.w);
        #pragma unroll
        for (int u = 0; u < 8; ++u) {
          a0 += bfu(u0[u]) * hv[u];
          a1 += bfu(u1[u]) * hv[u];
          a2 += bfu(u2[u]) * hv[u];
        }
      }
      pRed[(s4 * 3 + 0) * 64 + r] = a0;
      pRed[(s4 * 3 + 1) * 64 + r] = a1;
      pRed[(s4 * 3 + 2) * 64 + r] = a2;
    }
    __syncthreads();
    if (tid < 64) {
      const int r = tid;
      const float g0 = pRed[(0 * 3 + 0) * 64 + r] + pRed[(1 * 3 + 0) * 64 + r]
                     + pRed[(2 * 3 + 0) * 64 + r] + pRed[(3 * 3 + 0) * 64 + r]
                     + bih1[0 * 512 + j * 64 + r];
      const float g1 = pRed[(0 * 3 + 1) * 64 + r] + pRed[(1 * 3 + 1) * 64 + r]
                     + pRed[(2 * 3 + 1) * 64 + r] + pRed[(3 * 3 + 1) * 64 + r]
                     + bih1[1 * 512 + j * 64 + r];
      const float g2 = pRed[(0 * 3 + 2) * 64 + r] + pRed[(1 * 3 + 2) * 64 + r]
                     + pRed[(2 * 3 + 2) * 64 + r] + pRed[(3 * 3 + 2) * 64 + r]
                     + bih1[2 * 512 + j * 64 + r];
      const float rg = sigmoid_fast(g0 + gh1own[r]);
      const float zg = sigmoid_fast(g1 + gh1own[64 + r]);
      const float ng = tanh_fast(g2 + rg * gh1own[128 + r]);
      h1own[r] = (1.f - zg) * ng + zg * h1own[r];
    }
    __syncthreads();
    if (tid < 32) {
      const uint pk = packbf(h1own[2 * tid], h1own[2 * tid + 1]);
      h1u[j * 32 + tid] = pk;
      gstoreu(H1Qg + (size_t)j * 32 + tid, pk);
    }
    {
      float q0 = 0.f, q1 = 0.f;
      #pragma unroll
      for (int i = 0; i < 32; ++i) {
        const float hl = h1own[2 * i], hh = h1own[2 * i + 1];
        q0 += bflo(whq[i]) * hl + bfhi(whq[i]) * hh;
        q1 += bflo(whq[32 + i]) * hl + bfhi(whq[32 + i]) * hh;
      }
      gstoreu(QQg + (size_t)j * 256 + tid, packbf(q0, q1));
    }
    if (tid >= 64 && tid < 128) {
      const int lane = tid - 64, v = lane >> 4, i = lane & 15;
      float a = 0.f;
      #pragma unroll
      for (int k = 0; k < 4; ++k)
        a += Wout[(size_t)v * HH + j * 64 + i * 4 + k] * h1own[i * 4 + k];
      a += __shfl_xor(a, 8); a += __shfl_xor(a, 4);
      a += __shfl_xor(a, 2); a += __shfl_xor(a, 1);
      if (i == 0) lp[(((size_t)t * BB + b) * 8 + j) * 4 + v] = a;
    }
    octet_sync(ws, b, j, (uint)(3 * t + 4));
  }
}

// sum logit partials -> out
__global__ void k_lsum(const char* ws, const float* bout, float* out) {
  const float* lp = (const float*)(ws + OFF_LP);
  const int i = blockIdx.x * 256 + threadIdx.x;
  if (i >= BB * LL * VV) return;
  const int v = i & 3, t = (i >> 2) & 511, b = i >> 11;
  float a = bout[v];
  #pragma unroll
  for (int jj = 0; jj < 8; ++jj)
    a += lp[(((size_t)t * BB + b) * 8 + jj) * 4 + v];
  out[i] = a;
}

// ---------------- launch ----------------
extern "C" void kernel_launch(void* const* d_in, const int* in_sizes, int n_in,
                              void* d_out, int out_size, void* d_ws, size_t ws_size,
                              hipStream_t stream) {
  char* ws = (char*)d_ws;
  const float* enc     = (const float*)d_in[0];
  const int*   targets = (const int*)d_in[1];
  const float* emb   = (const float*)d_in[4];
  const float* Wh    = (const float*)d_in[5];
  const float* Ws    = (const float*)d_in[6];
  const float* vvec  = (const float*)d_in[7];
  const float* Wih0  = (const float*)d_in[8];
  const float* Whh0  = (const float*)d_in[9];
  const float* bih0  = (const float*)d_in[10];
  const float* bhh0  = (const float*)d_in[11];
  const float* Wih1  = (const float*)d_in[12];
  const float* Whh1  = (const float*)d_in[13];
  const float* bih1  = (const float*)d_in[14];
  const float* bhh1  = (const float*)d_in[15];
  const float* Wout  = (const float*)d_in[16];
  const float* bout  = (const float*)d_in[17];
  const float* Winit = (const float*)d_in[18];
  const float* binit = (const float*)d_in[19];

  k_prep <<<1024, 256, 0, stream>>>(Wh, Whh0, Wih0, Wih1, Whh1, ws);
  k_gitok<<<6,    256, 0, stream>>>(emb, Wih0, bih0, ws);
  k_keys <<<1024, 256, 0, stream>>>(enc, Ws, ws);
  k_init <<<64,   256, 0, stream>>>(enc, Winit, binit, ws);

  (void)hipFuncSetAttribute((const void*)k_decode,
                            hipFuncAttributeMaxDynamicSharedMemorySize, L_TOT);

  {
    void* kws = (void*)ws;
    void* ken = (void*)enc;
    void* ktg = (void*)targets;
    void* kvv = (void*)vvec;
    void* kb0 = (void*)bhh0;
    void* kb1 = (void*)bhh1;
    void* kbi = (void*)bih1;
    void* kwo = (void*)Wout;
    void* args[] = { &kws, &ken, &ktg, &kvv, &kb0, &kb1, &kbi, &kwo };
    hipError_t ce = hipLaunchCooperativeKernel((const void*)k_decode, dim3(NBLK), dim3(NTHR),
                                               args, L_TOT, stream);
    if (ce != hipSuccess) {
      // 512 blocks x (256 thr, 78.5KB LDS) = 2 blocks/CU on 256 CUs: co-resident
      k_decode<<<dim3(NBLK), dim3(NTHR), L_TOT, stream>>>(ws, enc, targets, vvec,
                                                          bhh0, bhh1, bih1, Wout);
    }
  }

  k_lsum<<<512, 256, 0, stream>>>(ws, bout, (float*)d_out);
}

// Round 9
// 49454.501 us; speedup vs baseline: 1.0921x; 1.0089x over previous
//
#include <hip/hip_runtime.h>
#include <cstdint>
#include <cstddef>

// GRU decoder w/ Bahdanau attention, B=64 L=512 E=128 H=512 ENC=256 V=4 NL=2.
// R9 = R7 (octet decomposition, agent-scope flag barriers — PROVEN) with all
// uncached exchanges vectorized to dwordx4 (sc0 sc1) and publishes staged
// through LDS: ~4x fewer coherence-point ops (the hypothesized wall).

#define BB   64
#define LL   512
#define EE   128
#define HH   512
#define ED   256
#define VV   4
#define SOS  4

#define NBLK 512
#define NTHR 256

typedef unsigned short ushort8 __attribute__((ext_vector_type(8)));
typedef unsigned int uint;
typedef uint  uint4v  __attribute__((ext_vector_type(4)));
typedef float float4v __attribute__((ext_vector_type(4)));

// ---------------- ws layout (bytes) ----------------
static const size_t OFF_KEYS = 0;          // ushort [64][512][512]  33,554,432
static const size_t OFF_WH   = 33554432;   // ushort [512][512]         524,288
static const size_t OFF_WHH0 = 34078720;   // ushort [1536][512]      1,572,864
static const size_t OFF_WIH1 = 35651584;   // ushort [1536][512]      1,572,864
static const size_t OFF_WHH1 = 37224448;   // ushort [1536][512]      1,572,864
static const size_t OFF_WIHC = 38797312;   // ushort [1536][256]        786,432
static const size_t OFF_GTOK = 39583744;   // float  [6][1536]           36,864
static const size_t OFF_H0   = 39620608;   // float  [64][512]          131,072
static const size_t OFF_H1   = 39751680;   // float  [64][512]          131,072
static const size_t OFF_QQ   = 39882752;   // uint   [64][8][256]       524,288
static const size_t OFF_CTXP = 40407040;   // float  [64][8][256]       524,288
static const size_t OFF_SS   = 40931328;   // float  [64][8]              2,048
static const size_t OFF_H0Q  = 40933376;   // uint   [64][8][32]         65,536
static const size_t OFF_H1Q  = 40998912;   // uint   [64][8][32]         65,536
static const size_t OFF_FLG  = 41064448;   // 64*8 x 64B                 32,768
static const size_t OFF_CNT  = 41097216;   // 8 x 64B                       512
static const size_t OFF_LP   = 41097728;   // f32 [512][64][8][4]     4,194,304

// ---------------- dynamic LDS layout (bytes) ----------------
#define L_KEYS 0          // 65536 swizzled keys eighth [64][512] bf16
#define L_H0F  65536      // 1024  h0 full bf16-packed uint[256]
#define L_H1F  66560      // 1024  h1 full bf16-packed uint[256]
#define L_QB   67584      // 2112  q f32 padded [4][132]
#define L_VV   69696      // 2112  v f32 padded [4][132]
#define L_CTX  71808      // 1024  ctx f32 [256] (also ctxp staging)
#define L_SCB  72832      // 256   scores [64] (also h pub staging)
#define L_ATB  73088      // 256   exp(scores) [64]
#define L_RED  73344      // 64    reduce scratch
#define L_PRED 73408      // 4096  pRed f32 [1024] (ctx merge / partials / q stage)
#define L_GH0  77504      // 768   gh0own [3][64]
#define L_GH1  78272      // 768   gh1own [3][64]
#define L_H0O  79040      // 256   h0own f32 [64]
#define L_H1O  79296      // 256   h1own f32 [64]
#define L_TOT  79552      // x2 blocks/CU = 159,104 <= 163,840

// ---------------- uncached (coherence-point) vectorized ops ----------------
#define UC_LD4(dst, ptr) \
  asm volatile("global_load_dwordx4 %0, %1, off sc0 sc1" : "=v"(dst) : "v"(ptr))
#define UC_ST4(ptr, v4) \
  asm volatile("global_store_dwordx4 %0, %1, off sc0 sc1" :: "v"(ptr), "v"(v4) : "memory")
#define UC_FENCE() \
  do { asm volatile("s_waitcnt vmcnt(0)" ::: "memory"); \
       __builtin_amdgcn_sched_barrier(0); } while (0)

// ---------------- helpers ----------------
__device__ __forceinline__ float bfu(unsigned short u) {
  return __uint_as_float(((unsigned)u) << 16);
}
__device__ __forceinline__ float bflo(uint u) { return __uint_as_float(u << 16); }
__device__ __forceinline__ float bfhi(uint u) { return __uint_as_float(u & 0xffff0000u); }
__device__ __forceinline__ unsigned short f2bf(float f) {
  unsigned u = __float_as_uint(f);
  unsigned r = 0x7FFFu + ((u >> 16) & 1u);
  return (unsigned short)((u + r) >> 16);
}
__device__ __forceinline__ uint packbf(float a, float b) {
  return (uint)f2bf(a) | ((uint)f2bf(b) << 16);
}
__device__ __forceinline__ float tanh_fast(float x) {
  x = __builtin_amdgcn_fmed3f(x, -10.f, 10.f);
  float t = __builtin_amdgcn_exp2f(x * 2.8853900817779268f);
  return (t - 1.f) * __builtin_amdgcn_rcpf(t + 1.f);
}
__device__ __forceinline__ float sigmoid_fast(float x) {
  x = __builtin_amdgcn_fmed3f(x, -30.f, 30.f);
  float t = __builtin_amdgcn_exp2f(x * -1.4426950408889634f);
  return __builtin_amdgcn_rcpf(1.f + t);
}
__device__ __forceinline__ float exp_fast(float x) {
  return __builtin_amdgcn_exp2f(x * 1.4426950408889634f);
}
__device__ __forceinline__ float gloadf(const float* p) {
  return __hip_atomic_load(p, __ATOMIC_RELAXED, __HIP_MEMORY_SCOPE_AGENT);
}
__device__ __forceinline__ void gstoref(float* p, float v) {
  __hip_atomic_store(p, v, __ATOMIC_RELAXED, __HIP_MEMORY_SCOPE_AGENT);
}
__device__ __forceinline__ uint gloadu(const uint* p) {
  return __hip_atomic_load(p, __ATOMIC_RELAXED, __HIP_MEMORY_SCOPE_AGENT);
}
__device__ __forceinline__ void gstoreu(uint* p, uint v) {
  __hip_atomic_store(p, v, __ATOMIC_RELAXED, __HIP_MEMORY_SCOPE_AGENT);
}

// octet barrier (R7-proven): drain vmem; tid0 publishes flag; lanes 0..7 poll
// the member flags in parallel with agent-scope relaxed loads.
__device__ __forceinline__ void octet_sync(char* ws, int b, int j, uint gen) {
  asm volatile("s_waitcnt vmcnt(0)" ::: "memory");
  __syncthreads();
  const int tid = threadIdx.x;
  uint* fl = (uint*)(ws + OFF_FLG);
  if (tid == 0)
    gstoreu(fl + (size_t)(b * 8 + j) * 16, gen);
  if (tid < 8 && tid != j) {
    while (gloadu(fl + (size_t)(b * 8 + tid) * 16) < gen)
      __builtin_amdgcn_s_sleep(4);
  }
  __syncthreads();
}

// ---------------- precompute kernels ----------------

__global__ void k_prep(const float* Wh, const float* Whh0, const float* Wih0,
                       const float* Wih1, const float* Whh1, char* ws) {
  unsigned short* Whbf   = (unsigned short*)(ws + OFF_WH);
  unsigned short* Whh0bf = (unsigned short*)(ws + OFF_WHH0);
  unsigned short* Wih1bf = (unsigned short*)(ws + OFF_WIH1);
  unsigned short* Whh1bf = (unsigned short*)(ws + OFF_WHH1);
  unsigned short* WihCbf = (unsigned short*)(ws + OFF_WIHC);
  const int tot = 262144 + 786432 * 3 + 393216;
  for (int i = blockIdx.x * blockDim.x + threadIdx.x; i < tot; i += gridDim.x * blockDim.x) {
    if (i < 262144) { Whbf[i] = f2bf(Wh[i]); }
    else if (i < 262144 + 786432) { int jj = i - 262144; Whh0bf[jj] = f2bf(Whh0[jj]); }
    else if (i < 262144 + 2 * 786432) { int jj = i - 262144 - 786432; Wih1bf[jj] = f2bf(Wih1[jj]); }
    else if (i < 262144 + 3 * 786432) { int jj = i - 262144 - 2 * 786432; Whh1bf[jj] = f2bf(Whh1[jj]); }
    else {
      int jj = i - 262144 - 3 * 786432;
      int r = jj >> 8, e = jj & 255;
      WihCbf[jj] = f2bf(Wih0[(size_t)r * 384 + 128 + e]);
    }
  }
}

__global__ void k_gitok(const float* emb, const float* Wih0, const float* bih0, char* ws) {
  float* gt = (float*)(ws + OFF_GTOK);
  const int vt = blockIdx.x;
  const int tid = threadIdx.x;
  __shared__ float ev[EE];
  if (tid < EE) ev[tid] = emb[(size_t)vt * EE + tid];
  __syncthreads();
  for (int r = tid; r < 1536; r += 256) {
    float a = bih0[r];
    const float* wr = Wih0 + (size_t)r * 384;
    for (int e = 0; e < EE; ++e) a += wr[e] * ev[e];
    gt[(size_t)vt * 1536 + r] = a;
  }
}

__global__ void k_keys(const float* enc, const float* Ws, char* ws) {
  unsigned short* keys = (unsigned short*)(ws + OFF_KEYS);
  __shared__ float et[32][ED];
  const int tid = threadIdx.x;
  const int row0 = blockIdx.x * 32;
  for (int r = 0; r < 32; ++r) et[r][tid] = enc[(size_t)(row0 + r) * ED + tid];
  __syncthreads();
  for (int hhh = 0; hhh < 2; ++hhh) {
    const int h = hhh * 256 + tid;
    float acc[32];
    #pragma unroll
    for (int ll = 0; ll < 32; ++ll) acc[ll] = 0.f;
    const float4* wrow = (const float4*)(Ws + (size_t)h * ED);
    for (int e4 = 0; e4 < 64; ++e4) {
      float4 w = wrow[e4];
      #pragma unroll
      for (int ll = 0; ll < 32; ++ll) {
        acc[ll] += w.x * et[ll][e4 * 4] + w.y * et[ll][e4 * 4 + 1]
                 + w.z * et[ll][e4 * 4 + 2] + w.w * et[ll][e4 * 4 + 3];
      }
    }
    for (int ll = 0; ll < 32; ++ll)
      keys[(size_t)(row0 + ll) * HH + h] = f2bf(acc[ll]);
  }
}

__global__ void k_init(const float* enc, const float* Winit, const float* binit, char* ws) {
  const int b = blockIdx.x;
  const int tid = threadIdx.x; // 256
  __shared__ float pooled[ED];
  float acc = 0.f;
  for (int l = 0; l < LL; ++l) acc += enc[((size_t)b * LL + l) * ED + tid];
  pooled[tid] = acc * (1.0f / 512.0f);
  __syncthreads();
  float* h0 = (float*)(ws + OFF_H0);
  float* h1 = (float*)(ws + OFF_H1);
  for (int pass = 0; pass < 4; ++pass) {
    const int jj = pass * 256 + tid;
    float a = binit[jj];
    const float* wr = Winit + (size_t)jj * ED;
    for (int e = 0; e < ED; ++e) a += wr[e] * pooled[e];
    const float val = tanh_fast(a);
    const int nl = jj >> 9, h = jj & 511;
    if (nl == 0) h0[(size_t)b * HH + h] = val;
    else h1[(size_t)b * HH + h] = val;
  }
  if (b == 0) {
    uint* fl = (uint*)(ws + OFF_FLG);
    for (int i = tid; i < 8192; i += 256) fl[i] = 0u;
    uint* cnt = (uint*)(ws + OFF_CNT);
    if (tid < 128) cnt[tid] = 0u;
  }
}

// ---------------- main persistent decoder ----------------
__launch_bounds__(NTHR, 2)
__global__ void k_decode(char* ws, const float* enc, const int* targets,
                         const float* vvec, const float* bhh0, const float* bhh1,
                         const float* bih1, const float* Wout) {
  extern __shared__ char smem[];
  const int tid = threadIdx.x;

  // XCD-aware roles (R7): j = XCC_ID, b = per-XCD rank.
  __shared__ int roleSh[2];
  if (tid == 0) {
    uint xcd;
    asm volatile("s_getreg_b32 %0, hwreg(HW_REG_XCC_ID)" : "=s"(xcd));
    xcd &= 7u;
    uint* cnt = (uint*)(ws + OFF_CNT);
    uint rank = __hip_atomic_fetch_add(cnt + (size_t)xcd * 16, 1u,
                                       __ATOMIC_RELAXED, __HIP_MEMORY_SCOPE_AGENT);
    roleSh[0] = (int)(rank & 63);
    roleSh[1] = (int)xcd;
  }
  __syncthreads();
  const int b = roleSh[0], j = roleSh[1];

  const unsigned short* keysg  = (const unsigned short*)(ws + OFF_KEYS);
  const unsigned short* Whbf   = (const unsigned short*)(ws + OFF_WH);
  const unsigned short* Whh0bf = (const unsigned short*)(ws + OFF_WHH0);
  const unsigned short* Wih1bf = (const unsigned short*)(ws + OFF_WIH1);
  const unsigned short* Whh1bf = (const unsigned short*)(ws + OFF_WHH1);
  const unsigned short* WihCbf = (const unsigned short*)(ws + OFF_WIHC);
  const float* gi_tok = (const float*)(ws + OFF_GTOK);

  uint*  QQg   = (uint*)(ws + OFF_QQ)   + (size_t)b * 2048;  // [8][256]
  float* CTXPg = (float*)(ws + OFF_CTXP) + (size_t)b * 2048; // [8][256]
  float* SSg   = (float*)(ws + OFF_SS)  + (size_t)b * 8;     // [8]
  uint*  H0Qg  = (uint*)(ws + OFF_H0Q)  + (size_t)b * 256;   // [8][32]
  uint*  H1Qg  = (uint*)(ws + OFF_H1Q)  + (size_t)b * 256;   // [8][32]
  float* lp    = (float*)(ws + OFF_LP);

  uint*  h0u   = (uint*)(smem + L_H0F);
  uint*  h1u   = (uint*)(smem + L_H1F);
  float* qbf   = (float*)(smem + L_QB);
  float* vvf   = (float*)(smem + L_VV);
  float* ctx   = (float*)(smem + L_CTX);
  float* scb   = (float*)(smem + L_SCB);
  float* atb   = (float*)(smem + L_ATB);
  float* wred  = (float*)(smem + L_RED);
  float* pRed  = (float*)(smem + L_PRED);
  float* gh0own = (float*)(smem + L_GH0);
  float* gh1own = (float*)(smem + L_GH1);
  float* h0own = (float*)(smem + L_H0O);
  float* h1own = (float*)(smem + L_H1O);
  uint*  qstage = (uint*)(smem + L_PRED);  // reuse (phase-exclusive)
  uint*  hstage = (uint*)(smem + L_SCB);   // reuse (phase-exclusive)

  // ---------- preloads (once) ----------
  for (int c = tid; c < 4096; c += NTHR) {
    const int l = c >> 6, hs = c & 63;
    ushort8 kv = *(const ushort8*)(keysg + ((size_t)(b * LL + j * 64 + l) * HH + hs * 8));
    *(ushort8*)(smem + L_KEYS + l * 1024 + ((hs * 16) ^ ((l & 7) << 4))) = kv;
  }
  for (int h = tid; h < 512; h += NTHR)
    vvf[(h >> 7) * 132 + (h & 127)] = vvec[h];
  {
    const float* H0g = (const float*)(ws + OFF_H0) + (size_t)b * HH;
    const float* H1g = (const float*)(ws + OFF_H1) + (size_t)b * HH;
    h0u[tid] = packbf(H0g[2 * tid], H0g[2 * tid + 1]);
    h1u[tid] = packbf(H1g[2 * tid], H1g[2 * tid + 1]);
    if (tid < 64) {
      h0own[tid] = H0g[j * 64 + tid];
      h1own[tid] = H1g[j * 64 + tid];
    }
  }
  uint encp[32];
  {
    const float* ebase = enc + ((size_t)(b * LL + j * 64)) * ED + tid;
    #pragma unroll
    for (int k = 0; k < 32; ++k)
      encp[k] = packbf(ebase[(size_t)(2 * k) * ED], ebase[(size_t)(2 * k + 1) * ED]);
  }
  uint whq[64];
  #pragma unroll
  for (int i = 0; i < 32; ++i) {
    whq[i]      = *(const uint*)(Whbf + (size_t)(2 * tid) * HH + j * 64 + 2 * i);
    whq[32 + i] = *(const uint*)(Whbf + (size_t)(2 * tid + 1) * HH + j * 64 + 2 * i);
  }
  __syncthreads();

  // pre-loop: publish q-parts + own h1 slice (phase C of step -1), x4-staged
  {
    float q0 = 0.f, q1 = 0.f;
    #pragma unroll
    for (int i = 0; i < 32; ++i) {
      const float hl = h1own[2 * i], hh = h1own[2 * i + 1];
      q0 += bflo(whq[i]) * hl + bfhi(whq[i]) * hh;
      q1 += bflo(whq[32 + i]) * hl + bfhi(whq[32 + i]) * hh;
    }
    qstage[tid] = packbf(q0, q1);
    if (tid < 32) hstage[tid] = packbf(h1own[2 * tid], h1own[2 * tid + 1]);
    __syncthreads();
    if (tid < 64) { UC_ST4(QQg + (size_t)j * 256 + 4 * tid, *(uint4v*)(qstage + 4 * tid)); }
    else if (tid < 72) {
      const int c = tid - 64;
      UC_ST4(H1Qg + (size_t)j * 32 + 4 * c, *(uint4v*)(hstage + 4 * c));
    }
  }
  octet_sync(ws, b, j, 1u);

  for (int t = 0; t < LL; ++t) {
    // ====== A1: q assembly (x4) + sibling h1 update (x4) ======
    if (tid < 64) {
      uint4v uq0, uq1, uq2, uq3, uq4, uq5, uq6, uq7;
      UC_LD4(uq0, QQg + 0 * 256 + 4 * tid);
      UC_LD4(uq1, QQg + 1 * 256 + 4 * tid);
      UC_LD4(uq2, QQg + 2 * 256 + 4 * tid);
      UC_LD4(uq3, QQg + 3 * 256 + 4 * tid);
      UC_LD4(uq4, QQg + 4 * 256 + 4 * tid);
      UC_LD4(uq5, QQg + 5 * 256 + 4 * tid);
      UC_LD4(uq6, QQg + 6 * 256 + 4 * tid);
      UC_LD4(uq7, QQg + 7 * 256 + 4 * tid);
      UC_FENCE();
      const int base = ((8 * tid) >> 7) * 132 + ((8 * tid) & 127);
      #pragma unroll
      for (int k = 0; k < 4; ++k) {
        float lo = bflo(uq0[k]) + bflo(uq1[k]) + bflo(uq2[k]) + bflo(uq3[k])
                 + bflo(uq4[k]) + bflo(uq5[k]) + bflo(uq6[k]) + bflo(uq7[k]);
        float hi = bfhi(uq0[k]) + bfhi(uq1[k]) + bfhi(uq2[k]) + bfhi(uq3[k])
                 + bfhi(uq4[k]) + bfhi(uq5[k]) + bfhi(uq6[k]) + bfhi(uq7[k]);
        qbf[base + 2 * k]     = lo;
        qbf[base + 2 * k + 1] = hi;
      }
    } else if (tid < 120) {
      const int p2 = (tid - 64) >> 3, c = (tid - 64) & 7;
      const int p = p2 + (p2 >= j);
      uint4v u;
      UC_LD4(u, H1Qg + (size_t)p * 32 + 4 * c);
      UC_FENCE();
      *(uint4v*)(h1u + p * 32 + 4 * c) = u;
    }
    __syncthreads();

    // ====== A2: gh0/gh1 K-half partials ======
    {
      const int mat = tid >> 7, seg = (tid >> 6) & 1, r = tid & 63;
      const unsigned short* W = mat ? Whh1bf : Whh0bf;
      const uint* hsrc = (mat ? h1u : h0u) + seg * 128;
      const ushort8* w0 = (const ushort8*)(W + (size_t)(0 * 512 + j * 64 + r) * 512 + seg * 256);
      const ushort8* w1 = (const ushort8*)(W + (size_t)(1 * 512 + j * 64 + r) * 512 + seg * 256);
      const ushort8* w2 = (const ushort8*)(W + (size_t)(2 * 512 + j * 64 + r) * 512 + seg * 256);
      float a0 = 0.f, a1 = 0.f, a2 = 0.f;
      for (int k8 = 0; k8 < 32; ++k8) {
        const uint4 hu = *(const uint4*)(hsrc + k8 * 4);
        const ushort8 u0 = w0[k8], u1 = w1[k8], u2 = w2[k8];
        float hv[8];
        hv[0] = bflo(hu.x); hv[1] = bfhi(hu.x); hv[2] = bflo(hu.y); hv[3] = bfhi(hu.y);
        hv[4] = bflo(hu.z); hv[5] = bfhi(hu.z); hv[6] = bflo(hu.w); hv[7] = bfhi(hu.w);
        #pragma unroll
        for (int u = 0; u < 8; ++u) {
          a0 += bfu(u0[u]) * hv[u];
          a1 += bfu(u1[u]) * hv[u];
          a2 += bfu(u2[u]) * hv[u];
        }
      }
      pRed[((mat * 2 + seg) * 3 + 0) * 64 + r] = a0;
      pRed[((mat * 2 + seg) * 3 + 1) * 64 + r] = a1;
      pRed[((mat * 2 + seg) * 3 + 2) * 64 + r] = a2;
    }

    // ====== A3: scores for own l-eighth ======
    {
      const int lloc = tid >> 2, hq = tid & 3;
      const char* kbase = smem + L_KEYS + lloc * 1024;
      const int xo = (lloc & 7) << 4;
      const float* qh = qbf + hq * 132;
      const float* vh = vvf + hq * 132;
      float s = 0.f;
      for (int i8 = 0; i8 < 16; ++i8) {
        ushort8 kk = *(const ushort8*)(kbase + ((hq * 256 + i8 * 16) ^ xo));
        const float* q8 = qh + i8 * 8;
        const float* v8 = vh + i8 * 8;
        #pragma unroll
        for (int u = 0; u < 8; ++u)
          s += v8[u] * tanh_fast(q8[u] + bfu(kk[u]));
      }
      s += __shfl_xor(s, 1);
      s += __shfl_xor(s, 2);
      if (hq == 0) scb[lloc] = s;
    }
    __syncthreads();

    // ====== A4: exp (no max pass; |s| <~ 20) + sum -> SS ======
    if (tid < 64) {
      float e = exp_fast(scb[tid]);
      atb[tid] = e;
      float s2 = e;
      #pragma unroll
      for (int off = 32; off >= 1; off >>= 1) s2 += __shfl_xor(s2, off);
      if (tid == 0) gstoref(SSg + j, s2);
    }
    __syncthreads();

    // ====== A5: ctx partial -> LDS stage -> x4 publish; gh reduce ======
    {
      float a = 0.f;
      #pragma unroll
      for (int k = 0; k < 32; ++k) {
        uint u = encp[k];
        a += atb[2 * k] * bflo(u) + atb[2 * k + 1] * bfhi(u);
      }
      ctx[tid] = a;   // stage (consumed by x4 store below; B overwrites later)
    }
    for (int o = tid; o < 384; o += NTHR) {
      const int m = (o >= 192) ? 1 : 0, oo = o - m * 192, g = oo >> 6, r = oo & 63;
      const float v = pRed[((m * 2 + 0) * 3 + g) * 64 + r]
                    + pRed[((m * 2 + 1) * 3 + g) * 64 + r]
                    + (m ? bhh1 : bhh0)[g * 512 + j * 64 + r];
      (m ? gh1own : gh0own)[g * 64 + r] = v;
    }
    __syncthreads();
    if (tid < 64) { UC_ST4((uint*)(CTXPg + (size_t)j * 256) + 4 * tid, *(uint4v*)((uint*)ctx + 4 * tid)); }
    octet_sync(ws, b, j, (uint)(3 * t + 2));

    // ====== B: ctx merge (x4) + gi0 + layer-0 gates ======
    {
      const int c = tid & 63, p0 = tid >> 6;
      float4v f0, f1;
      UC_LD4(f0, (const uint*)(CTXPg + (size_t)p0 * 256) + 4 * c);
      UC_LD4(f1, (const uint*)(CTXPg + (size_t)(p0 + 4) * 256) + 4 * c);
      float ssv = 0.f;
      if (tid < 8) ssv = gloadf(SSg + tid);
      UC_FENCE();
      if (tid < 8) wred[tid] = ssv;
      *(float4v*)(pRed + (size_t)p0 * 256 + 4 * c) = f0 + f1;
      __syncthreads();
      const float S8 = ((wred[0] + wred[1]) + (wred[2] + wred[3]))
                     + ((wred[4] + wred[5]) + (wred[6] + wred[7]));
      const float rS = __builtin_amdgcn_rcpf(S8);
      ctx[tid] = (pRed[0 * 256 + tid] + pRed[1 * 256 + tid]
                + pRed[2 * 256 + tid] + pRed[3 * 256 + tid]) * rS;
    }
    __syncthreads();
    {
      const int r = tid & 63, q4 = tid >> 6;
      const ushort8* w0 = (const ushort8*)(WihCbf + (size_t)(0 * 512 + j * 64 + r) * 256 + q4 * 64);
      const ushort8* w1 = (const ushort8*)(WihCbf + (size_t)(1 * 512 + j * 64 + r) * 256 + q4 * 64);
      const ushort8* w2 = (const ushort8*)(WihCbf + (size_t)(2 * 512 + j * 64 + r) * 256 + q4 * 64);
      const float* cx = ctx + q4 * 64;
      float a0 = 0.f, a1 = 0.f, a2 = 0.f;
      for (int k8 = 0; k8 < 8; ++k8) {
        const ushort8 u0 = w0[k8], u1 = w1[k8], u2 = w2[k8];
        #pragma unroll
        for (int u = 0; u < 8; ++u) {
          const float c = cx[k8 * 8 + u];
          a0 += bfu(u0[u]) * c; a1 += bfu(u1[u]) * c; a2 += bfu(u2[u]) * c;
        }
      }
      pRed[(q4 * 3 + 0) * 64 + r] = a0;
      pRed[(q4 * 3 + 1) * 64 + r] = a1;
      pRed[(q4 * 3 + 2) * 64 + r] = a2;
    }
    __syncthreads();
    if (tid < 64) {
      const int r = tid;
      const int tok = (t == 0) ? SOS : targets[(size_t)b * LL + t - 1];
      const float* gt = gi_tok + (size_t)tok * 1536 + j * 64 + r;
      const float g0 = pRed[(0 * 3 + 0) * 64 + r] + pRed[(1 * 3 + 0) * 64 + r]
                     + pRed[(2 * 3 + 0) * 64 + r] + pRed[(3 * 3 + 0) * 64 + r] + gt[0];
      const float g1 = pRed[(0 * 3 + 1) * 64 + r] + pRed[(1 * 3 + 1) * 64 + r]
                     + pRed[(2 * 3 + 1) * 64 + r] + pRed[(3 * 3 + 1) * 64 + r] + gt[512];
      const float g2 = pRed[(0 * 3 + 2) * 64 + r] + pRed[(1 * 3 + 2) * 64 + r]
                     + pRed[(2 * 3 + 2) * 64 + r] + pRed[(3 * 3 + 2) * 64 + r] + gt[1024];
      const float rg = sigmoid_fast(g0 + gh0own[r]);
      const float zg = sigmoid_fast(g1 + gh0own[64 + r]);
      const float ng = tanh_fast(g2 + rg * gh0own[128 + r]);
      h0own[r] = (1.f - zg) * ng + zg * h0own[r];
    }
    __syncthreads();
    if (tid < 32) {
      const uint pk = packbf(h0own[2 * tid], h0own[2 * tid + 1]);
      h0u[j * 32 + tid] = pk;
      hstage[tid] = pk;
    }
    __syncthreads();
    if (tid < 8) { UC_ST4(H0Qg + (size_t)j * 32 + 4 * tid, *(uint4v*)(hstage + 4 * tid)); }
    octet_sync(ws, b, j, (uint)(3 * t + 3));

    // ====== C: sibling h0 (x4) + gi1 + layer-1 gates + q/h1 publish ======
    if (tid < 56) {
      const int p2 = tid >> 3, c = tid & 7;
      const int p = p2 + (p2 >= j);
      uint4v u;
      UC_LD4(u, H0Qg + (size_t)p * 32 + 4 * c);
      UC_FENCE();
      *(uint4v*)(h0u + p * 32 + 4 * c) = u;
    }
    __syncthreads();
    {
      const int r = tid & 63, s4 = tid >> 6;
      const ushort8* w0 = (const ushort8*)(Wih1bf + (size_t)(0 * 512 + j * 64 + r) * 512 + s4 * 128);
      const ushort8* w1 = (const ushort8*)(Wih1bf + (size_t)(1 * 512 + j * 64 + r) * 512 + s4 * 128);
      const ushort8* w2 = (const ushort8*)(Wih1bf + (size_t)(2 * 512 + j * 64 + r) * 512 + s4 * 128);
      const uint* hsrc = h0u + s4 * 64;
      float a0 = 0.f, a1 = 0.f, a2 = 0.f;
      for (int k8 = 0; k8 < 16; ++k8) {
        const uint4 hu = *(const uint4*)(hsrc + k8 * 4);
        const ushort8 u0 = w0[k8], u1 = w1[k8], u2 = w2[k8];
        float hv[8];
        hv[0] = bflo(hu.x); hv[1] = bfhi(hu.x); hv[2] = bflo(hu.y); hv[3] = bfhi(hu.y);
        hv[4] = bflo(hu.z); hv[5] = bfhi(hu.z); hv[6] = bflo(hu.w); hv[7] = bfhi(hu.w);
        #pragma unroll
        for (int u = 0; u < 8; ++u) {
          a0 += bfu(u0[u]) * hv[u];
          a1 += bfu(u1[u]) * hv[u];
          a2 += bfu(u2[u]) * hv[u];
        }
      }
      pRed[(s4 * 3 + 0) * 64 + r] = a0;
      pRed[(s4 * 3 + 1) * 64 + r] = a1;
      pRed[(s4 * 3 + 2) * 64 + r] = a2;
    }
    __syncthreads();
    if (tid < 64) {
      const int r = tid;
      const float g0 = pRed[(0 * 3 + 0) * 64 + r] + pRed[(1 * 3 + 0) * 64 + r]
                     + pRed[(2 * 3 + 0) * 64 + r] + pRed[(3 * 3 + 0) * 64 + r]
                     + bih1[0 * 512 + j * 64 + r];
      const float g1 = pRed[(0 * 3 + 1) * 64 + r] + pRed[(1 * 3 + 1) * 64 + r]
                     + pRed[(2 * 3 + 1) * 64 + r] + pRed[(3 * 3 + 1) * 64 + r]
                     + bih1[1 * 512 + j * 64 + r];
      const float g2 = pRed[(0 * 3 + 2) * 64 + r] + pRed[(1 * 3 + 2) * 64 + r]
                     + pRed[(2 * 3 + 2) * 64 + r] + pRed[(3 * 3 + 2) * 64 + r]
                     + bih1[2 * 512 + j * 64 + r];
      const float rg = sigmoid_fast(g0 + gh1own[r]);
      const float zg = sigmoid_fast(g1 + gh1own[64 + r]);
      const float ng = tanh_fast(g2 + rg * gh1own[128 + r]);
      h1own[r] = (1.f - zg) * ng + zg * h1own[r];
    }
    __syncthreads();
    {
      float q0 = 0.f, q1 = 0.f;
      #pragma unroll
      for (int i = 0; i < 32; ++i) {
        const float hl = h1own[2 * i], hh = h1own[2 * i + 1];
        q0 += bflo(whq[i]) * hl + bfhi(whq[i]) * hh;
        q1 += bflo(whq[32 + i]) * hl + bfhi(whq[32 + i]) * hh;
      }
      qstage[tid] = packbf(q0, q1);
    }
    if (tid < 32) {
      const uint pk = packbf(h1own[2 * tid], h1own[2 * tid + 1]);
      h1u[j * 32 + tid] = pk;
      hstage[tid] = pk;
    }
    // logit partials (independent of staging buffers)
    if (tid >= 64 && tid < 128) {
      const int lane = tid - 64, v = lane >> 4, i = lane & 15;
      float a = 0.f;
      #pragma unroll
      for (int k = 0; k < 4; ++k)
        a += Wout[(size_t)v * HH + j * 64 + i * 4 + k] * h1own[i * 4 + k];
      a += __shfl_xor(a, 8); a += __shfl_xor(a, 4);
      a += __shfl_xor(a, 2); a += __shfl_xor(a, 1);
      if (i == 0) lp[(((size_t)t * BB + b) * 8 + j) * 4 + v] = a;
    }
    __syncthreads();
    if (tid < 64) { UC_ST4(QQg + (size_t)j * 256 + 4 * tid, *(uint4v*)(qstage + 4 * tid)); }
    else if (tid < 72) {
      const int c = tid - 64;
      UC_ST4(H1Qg + (size_t)j * 32 + 4 * c, *(uint4v*)(hstage + 4 * c));
    }
    octet_sync(ws, b, j, (uint)(3 * t + 4));
  }
}

// sum logit partials -> out
__global__ void k_lsum(const char* ws, const float* bout, float* out) {
  const float* lp = (const float*)(ws + OFF_LP);
  const int i = blockIdx.x * 256 + threadIdx.x;
  if (i >= BB * LL * VV) return;
  const int v = i & 3, t = (i >> 2) & 511, b = i >> 11;
  float a = bout[v];
  #pragma unroll
  for (int jj = 0; jj < 8; ++jj)
    a += lp[(((size_t)t * BB + b) * 8 + jj) * 4 + v];
  out[i] = a;
}

// ---------------- launch ----------------
extern "C" void kernel_launch(void* const* d_in, const int* in_sizes, int n_in,
                              void* d_out, int out_size, void* d_ws, size_t ws_size,
                              hipStream_t stream) {
  char* ws = (char*)d_ws;
  const float* enc     = (const float*)d_in[0];
  const int*   targets = (const int*)d_in[1];
  const float* emb   = (const float*)d_in[4];
  const float* Wh    = (const float*)d_in[5];
  const float* Ws    = (const float*)d_in[6];
  const float* vvec  = (const float*)d_in[7];
  const float* Wih0  = (const float*)d_in[8];
  const float* Whh0  = (const float*)d_in[9];
  const float* bih0  = (const float*)d_in[10];
  const float* bhh0  = (const float*)d_in[11];
  const float* Wih1  = (const float*)d_in[12];
  const float* Whh1  = (const float*)d_in[13];
  const float* bih1  = (const float*)d_in[14];
  const float* bhh1  = (const float*)d_in[15];
  const float* Wout  = (const float*)d_in[16];
  const float* bout  = (const float*)d_in[17];
  const float* Winit = (const float*)d_in[18];
  const float* binit = (const float*)d_in[19];

  k_prep <<<1024, 256, 0, stream>>>(Wh, Whh0, Wih0, Wih1, Whh1, ws);
  k_gitok<<<6,    256, 0, stream>>>(emb, Wih0, bih0, ws);
  k_keys <<<1024, 256, 0, stream>>>(enc, Ws, ws);
  k_init <<<64,   256, 0, stream>>>(enc, Winit, binit, ws);

  (void)hipFuncSetAttribute((const void*)k_decode,
                            hipFuncAttributeMaxDynamicSharedMemorySize, L_TOT);

  {
    void* kws = (void*)ws;
    void* ken = (void*)enc;
    void* ktg = (void*)targets;
    void* kvv = (void*)vvec;
    void* kb0 = (void*)bhh0;
    void* kb1 = (void*)bhh1;
    void* kbi = (void*)bih1;
    void* kwo = (void*)Wout;
    void* args[] = { &kws, &ken, &ktg, &kvv, &kb0, &kb1, &kbi, &kwo };
    hipError_t ce = hipLaunchCooperativeKernel((const void*)k_decode, dim3(NBLK), dim3(NTHR),
                                               args, L_TOT, stream);
    if (ce != hipSuccess) {
      // 512 blocks x (256 thr, 79.5KB LDS) = 2 blocks/CU on 256 CUs: co-resident
      k_decode<<<dim3(NBLK), dim3(NTHR), L_TOT, stream>>>(ws, enc, targets, vvec,
                                                          bhh0, bhh1, bih1, Wout);
    }
  }

  k_lsum<<<512, 256, 0, stream>>>(ws, bout, (float*)d_out);
}